// Round 5
// baseline (254.330 us; speedup 1.0000x reference)
//
#include <hip/hip_runtime.h>

#define NPTS 100000
#define PB 64                         // points per block
#define NBLK ((NPTS + PB - 1) / PB)   // 1563
#define INF 1280
#define PSTR 544                      // sF per-point stride (512 + 32 pad)

using short8 = __attribute__((ext_vector_type(8))) short;
using f32x4  = __attribute__((ext_vector_type(4))) float;

__device__ __forceinline__ unsigned short f2bf(float x) {
  unsigned u = __float_as_uint(x);
  return (unsigned short)((u + 0x7FFFu + ((u >> 16) & 1u)) >> 16);  // RNE
}
__device__ __forceinline__ unsigned pack2(float a, float b) {
  return (unsigned)f2bf(a) | ((unsigned)f2bf(b) << 16);
}

// ---- prep: in_f f32 -> bf16 (12.8 MB, L3-resident for gathers) ----
__global__ void k_prep(const float* __restrict__ in_f, unsigned short* __restrict__ inbf) {
  int i = blockIdx.x * 256 + threadIdx.x;
  if (i < 1600000) {
    float4 v = ((const float4*)in_f)[i];
    ushort4 o;
    o.x = f2bf(v.x); o.y = f2bf(v.y); o.z = f2bf(v.z); o.w = f2bf(v.w);
    ((ushort4*)inbf)[i] = o;
  }
}

// ---- retile linear_weights -> bf16 B-fragment order (R2-verified) ----
// Wb[nt][ct][ks 0..31][col 0..15][j 0..7]; k^=ks*8+j; m=k^>>4; ci=k^&15
__global__ void k_wconv(const float* __restrict__ W, unsigned short* __restrict__ Wb) {
  int g = blockIdx.x * 256 + threadIdx.x;   // 0..327679
  int j = g & 7;
  int col = (g >> 3) & 15;
  int ks = (g >> 7) & 31;
  int rest = g >> 12;
  int ct = rest % 5, nt = rest / 5;
  int kh = ks * 8 + j;
  int m = kh >> 4, ci = kh & 15;
  Wb[g] = f2bf(W[(nt * 16 + col) * INF + (ct * 16 + ci) * 16 + m]);
}

// ---- fused: gather+concat+pconv (MFMA) + linear (MFMA); no inline asm ----
// sF[p][x 0..15][k 0..15] bf16, x = c-within-slice or wn m; k innermost so
// fragments are single ds_read_b128. Transpose happens on the write side
// (8x ds_write_b16 per staged granule, ~4-way conflicts with the 544 pad).
__global__ __launch_bounds__(512, 4) void k_fused(
    const unsigned short* __restrict__ inbf, const int* __restrict__ nbr,
    const float* __restrict__ wn_g, const float* __restrict__ add_f,
    const unsigned short* __restrict__ Wb, const float* __restrict__ bias,
    float* __restrict__ out)
{
  __shared__ __align__(16) unsigned char sF[PB * PSTR];  // 34816 B
  __shared__ __align__(16) unsigned char sA[PB * 528];   // 33792 B

  const int t = threadIdx.x;
  const int w = t >> 6, lane = t & 63;
  const int g16 = lane >> 4, c16 = lane & 15;
  const long p0 = (long)blockIdx.x * PB;

  // staging geometry: 4 units/thread; unit = (p, k, h): 8 x-values (h half)
  int uidx[4], upp[4];
#pragma unroll
  for (int i = 0; i < 4; ++i) {
    int flat = i * 512 + t;
    long pp = p0 + (flat >> 5); if (pp >= NPTS) pp = NPTS - 1;
    upp[i] = (int)pp;
    uidx[i] = nbr[pp * 16 + ((flat >> 1) & 15)];
  }

  uint4 sr[4];
  auto gload = [&](int ct) {             // gather ct-slice, 16B granules
#pragma unroll
    for (int i = 0; i < 4; ++i) {
      int uh = (i * 512 + t) & 1;
      sr[i] = *(const uint4*)(inbf + (long)uidx[i] * 64 + ct * 16 + uh * 8);
    }
  };
  auto fload = [&]() {                   // add_f slice (f32->bf16)
#pragma unroll
    for (int i = 0; i < 4; ++i) {
      int flat = i * 512 + t, uk = (flat >> 1) & 15, uh = flat & 1;
      const float* s = add_f + (long)upp[i] * 256 + uk * 16 + uh * 8;
      float4 a = *(const float4*)s, b = *(const float4*)(s + 4);
      sr[i] = make_uint4(pack2(a.x, a.y), pack2(a.z, a.w), pack2(b.x, b.y), pack2(b.z, b.w));
    }
  };
  auto swrite = [&]() {                  // transpose-scatter into [x][k]
#pragma unroll
    for (int i = 0; i < 4; ++i) {
      int flat = i * 512 + t, up = flat >> 5, uk = (flat >> 1) & 15, uh = flat & 1;
      unsigned char* base = sF + up * PSTR + uh * 256 + uk * 2;
      *(unsigned short*)(base +   0) = (unsigned short)(sr[i].x);
      *(unsigned short*)(base +  32) = (unsigned short)(sr[i].x >> 16);
      *(unsigned short*)(base +  64) = (unsigned short)(sr[i].y);
      *(unsigned short*)(base +  96) = (unsigned short)(sr[i].y >> 16);
      *(unsigned short*)(base + 128) = (unsigned short)(sr[i].z);
      *(unsigned short*)(base + 160) = (unsigned short)(sr[i].z >> 16);
      *(unsigned short*)(base + 192) = (unsigned short)(sr[i].w);
      *(unsigned short*)(base + 224) = (unsigned short)(sr[i].w >> 16);
    }
  };

  // ---- issue first gather early (T14), then stage wn into sF [p][m][k] ----
  gload(0);
#pragma unroll
  for (int i = 0; i < 4; ++i) {
    int flat = i * 512 + t, up = flat >> 5, uk = (flat >> 1) & 15, uh = flat & 1;
    const float* s = wn_g + (long)upp[i] * 256 + uk * 16 + uh * 8;
    float4 a = *(const float4*)s, b = *(const float4*)(s + 4);
    unsigned char* base = sF + up * PSTR + uh * 256 + uk * 2;
    *(unsigned short*)(base +   0) = f2bf(a.x);
    *(unsigned short*)(base +  32) = f2bf(a.y);
    *(unsigned short*)(base +  64) = f2bf(a.z);
    *(unsigned short*)(base +  96) = f2bf(a.w);
    *(unsigned short*)(base + 128) = f2bf(b.x);
    *(unsigned short*)(base + 160) = f2bf(b.y);
    *(unsigned short*)(base + 192) = f2bf(b.z);
    *(unsigned short*)(base + 224) = f2bf(b.w);
  }
  __syncthreads();   // wn staged

  // ---- preload wn B-fragments for this wave's 8 points (registers) ----
  short8 bfr[8];
#pragma unroll
  for (int i = 0; i < 8; ++i) {
    bfr[i] = (short8){0, 0, 0, 0, 0, 0, 0, 0};
    if (g16 < 2)
      bfr[i] = *(const short8*)(sF + (w * 8 + i) * PSTR + c16 * 32 + g16 * 16);
  }
  __syncthreads();   // all waves done reading wn; sF reusable

  auto pconv = [&]() {                   // per wave: 8 points, 1 MFMA each
#pragma unroll
    for (int g = 0; g < 2; ++g) {
      short8 af[4];
#pragma unroll
      for (int i = 0; i < 4; ++i) {
        af[i] = (short8){0, 0, 0, 0, 0, 0, 0, 0};
        if (g16 < 2)
          af[i] = *(const short8*)(sF + (w * 8 + g * 4 + i) * PSTR + c16 * 32 + g16 * 16);
      }
#pragma unroll
      for (int i = 0; i < 4; ++i) {
        int p = w * 8 + g * 4 + i;
        f32x4 d = __builtin_amdgcn_mfma_f32_16x16x32_bf16(
            af[i], bfr[g * 4 + i], (f32x4){0.f, 0.f, 0.f, 0.f}, 0, 0, 0);
        // D: row(c)=g16*4+r, col(m)=c16; k^=m*16+c -> byte c16*32+g16*8+r*2
        *(uint2*)(sA + p * 528 + c16 * 32 + g16 * 8) =
            make_uint2(pack2(d[0], d[1]), pack2(d[2], d[3]));
      }
    }
  };

  f32x4 acc[4][2];
#pragma unroll
  for (int rr = 0; rr < 4; ++rr)
#pragma unroll
    for (int ntl = 0; ntl < 2; ++ntl) acc[rr][ntl] = (f32x4){0.f, 0.f, 0.f, 0.f};

  auto gemm = [&](int ct) {              // wave: 4 row-tiles x 2 col-tiles
#pragma unroll
    for (int kl = 0; kl < 8; ++kl) {
      short8 a[4];
#pragma unroll
      for (int rr = 0; rr < 4; ++rr)
        a[rr] = *(const short8*)(sA + (rr * 16 + c16) * 528 + kl * 64 + g16 * 16);
#pragma unroll
      for (int ntl = 0; ntl < 2; ++ntl) {
        int nt = w * 2 + ntl;
        short8 b = *(const short8*)(Wb + ((long)((nt * 5 + ct) * 32 + kl * 4 + g16) * 16 + c16) * 8);
#pragma unroll
        for (int rr = 0; rr < 4; ++rr)
          acc[rr][ntl] = __builtin_amdgcn_mfma_f32_16x16x32_bf16(a[rr], b, acc[rr][ntl], 0, 0, 0);
      }
    }
  };

  // ---- main schedule (R2-proven barrier pattern + T14 split staging) ----
  swrite();            // sF(0) features
  __syncthreads();
  pconv();
  __syncthreads();     // sA(0) ready
  for (int ct = 0; ct < 5; ++ct) {
    if (ct < 3) gload(ct + 1);           // issue-early
    else if (ct == 3) fload();
    gemm(ct);
    if (ct < 4) {
      swrite();                          // write-late
      __syncthreads();                   // sF(ct+1) ready, sA consumed
      pconv();
      __syncthreads();                   // sA(ct+1) ready
    }
  }

  // ---- epilogue ----
#pragma unroll
  for (int ntl = 0; ntl < 2; ++ntl) {
    int n = (w * 2 + ntl) * 16 + c16;
    float bv = bias[n];
#pragma unroll
    for (int rr = 0; rr < 4; ++rr) {
      long prow = p0 + rr * 16 + g16 * 4;
#pragma unroll
      for (int r = 0; r < 4; ++r)
        if (prow + r < NPTS) out[(prow + r) * 256 + n] = acc[rr][ntl][r] + bv;
    }
  }
}

extern "C" void kernel_launch(void* const* d_in, const int* in_sizes, int n_in,
                              void* d_out, int out_size, void* d_ws, size_t ws_size,
                              hipStream_t stream) {
  const float* in_f  = (const float*)d_in[0];
  const int*   nbr   = (const int*)d_in[1];
  const float* wn    = (const float*)d_in[5];
  const float* add_f = (const float*)d_in[6];
  const float* W     = (const float*)d_in[7];
  const float* bias  = (const float*)d_in[8];
  float* out = (float*)d_out;

  unsigned short* inbf = (unsigned short*)d_ws;                       // 12.8 MB
  unsigned short* Wb   = (unsigned short*)((char*)d_ws + 13631488);   // 640 KB

  k_prep<<<dim3(6250), dim3(256), 0, stream>>>(in_f, inbf);
  k_wconv<<<dim3(1280), dim3(256), 0, stream>>>(W, Wb);
  k_fused<<<dim3(NBLK), dim3(512), 0, stream>>>(inbf, nbr, wn, add_f, Wb, bias, out);
}